// Round 10
// baseline (38195.175 us; speedup 1.0000x reference)
//
#include <hip/hip_runtime.h>
#include <math.h>

#define B_  64
#define T_  512
#define D0_ 128
#define H_  512
#define G3_ 1536
#define HSTR 512
#define BKg 32
#define SENT 0x7FC00000u   // NaN sentinel; |h|<1 strictly so real h never matches

typedef short short8 __attribute__((ext_vector_type(8)));
typedef float f32x4 __attribute__((ext_vector_type(4)));

// ---------------- scan kernel (data-as-flag + 4x32 retile) ----------------
// 256 blocks = 16 groups x 16 blocks; plain launch; 1 block/CU (capacity 1).
// Thread (rp in [0,24), s in [0,16)): 4 gate-rows {rp+24m}, k-slice of 32
// (k = kk*64 + s*4 + q), all 4 batches -> 32 b128 h-reads/step (half of R8).
// launch_bounds(384,1): lifts the 128-VGPR cap that made R4's retile spill
// (w[4][32]=128 regs + accs now fit in <=256 VGPRs; 6 waves still 1 block/CU).
__global__ __launch_bounds__(384, 1) void scan_kernel(
    const float* __restrict__ Whh, const float* __restrict__ bhh,
    const float* __restrict__ gx, float* __restrict__ hist,
    int t0, int tc, int gxt0, int gxT)
{
  __shared__ float hsh[4 * HSTR];
  __shared__ float ghsh[96 * 5];
  __shared__ float bsh[96];

  const int tid = threadIdx.x;
  const int blk = blockIdx.x;
  const int g = blk >> 4, c = blk & 15;
  const int j0 = c << 5;
  const int bbase = g << 2;

  const int rp = tid >> 4, s = tid & 15;

  // W_hh: 4 rows x 32 k in registers. k = kk*64 + s*4 + q.
  float w[4][32];
  #pragma unroll
  for (int m = 0; m < 4; ++m) {
    int r = rp + 24 * m;
    const float* R = Whh + (size_t)((r >> 5) * H_ + j0 + (r & 31)) * H_ + (s << 2);
    #pragma unroll
    for (int kk = 0; kk < 8; ++kk)
      *(float4*)&w[m][kk * 4] = *(const float4*)(R + kk * 64);
  }
  if (tid < 96)
    bsh[tid] = bhh[(tid >> 5) * H_ + j0 + (tid & 31)];

  size_t go0 = 0;
  if (tid < 128) {
    int bb = tid >> 5, j = tid & 31;
    go0 = ((size_t)(bbase + bb) * gxT) * (size_t)G3_ + j0 + j;
  }
  __syncthreads();

  for (int t = t0; t < t0 + tc; ++t) {
    // ---- gx prefetch (independent of exchange) ----
    float gxr = 0.f, gxz = 0.f, gxn = 0.f;
    if (tid < 128) {
      size_t go = go0 + (size_t)(t - gxt0) * (size_t)G3_;
      gxr = gx[go]; gxz = gx[go + 512]; gxn = gx[go + 1024];
    }

    // ---- stage h_prev into LDS: poll b64 pairs of the data itself ----
    if (t == 0) {
      for (int idx = tid; idx < 2048; idx += 384)
        hsh[(idx >> 9) * HSTR + (idx & 511)] = 0.f;
    } else {
      unsigned rem = 0;
      #pragma unroll
      for (int p = 0; p < 3; ++p)
        if (tid + p * 384 < 1024) rem |= 1u << p;
      unsigned long long vals[3];
      while (rem) {
        #pragma unroll
        for (int p = 0; p < 3; ++p)
          if (rem & (1u << p)) {
            int idx = tid + p * 384;              // pair index
            int bb = idx >> 8, e2 = idx & 255;    // batch, pair-in-row
            vals[p] = __hip_atomic_load(
                (const unsigned long long*)(hist +
                    ((size_t)(bbase + bb) * T_ + (t - 1)) * H_) + e2,
                __ATOMIC_RELAXED, __HIP_MEMORY_SCOPE_AGENT);
          }
        #pragma unroll
        for (int p = 0; p < 3; ++p)
          if (rem & (1u << p)) {
            unsigned lo = (unsigned)vals[p], hi = (unsigned)(vals[p] >> 32);
            if (lo != SENT && hi != SENT) {
              int idx = tid + p * 384;
              int bb = idx >> 8, e2 = idx & 255;
              *(float2*)&hsh[bb * HSTR + (e2 << 1)] =
                  make_float2(__uint_as_float(lo), __uint_as_float(hi));
              rem &= ~(1u << p);
            }
          }
      }
    }
    __syncthreads();

    // ---- dots: v[m*4+b], h4 reused across the 4 rows ----
    float v[16];
    #pragma unroll
    for (int i = 0; i < 16; ++i) v[i] = 0.f;
    #pragma unroll
    for (int b = 0; b < 4; ++b) {
      const float* hb = hsh + b * HSTR + (s << 2);
      #pragma unroll
      for (int kk = 0; kk < 8; ++kk) {
        float4 h4 = *(const float4*)(hb + kk * 64);
        #pragma unroll
        for (int m = 0; m < 4; ++m) {
          v[m*4+b] += w[m][kk*4+0] * h4.x;
          v[m*4+b] += w[m][kk*4+1] * h4.y;
          v[m*4+b] += w[m][kk*4+2] * h4.z;
          v[m*4+b] += w[m][kk*4+3] * h4.w;
        }
      }
    }

    // ---- value-splitting butterfly over the 16 s-lanes (R4-verified) ----
    #pragma unroll
    for (int lvl = 0; lvl < 4; ++lvl) {
      const int mask = 1 << lvl, half = 8 >> lvl;
      const bool hi = (s & mask) != 0;
      #pragma unroll
      for (int i = 0; i < half; ++i) {
        float send = hi ? v[i] : v[i + half];
        float recv = __shfl_xor(send, mask, 64);
        v[i] = (hi ? v[i + half] : v[i]) + recv;
      }
    }
    {
      // lane s ends holding sum of original v[bitrev4(s)]
      int idx = ((s & 1) << 3) | ((s & 2) << 1) | ((s & 4) >> 1) | ((s & 8) >> 3);
      int msel = idx >> 2, bsel = idx & 3;
      ghsh[(rp + 24 * msel) * 5 + bsel] = v[0];
    }
    __syncthreads();

    // ---- gates + h_new; the store IS the cross-block signal ----
    if (tid < 128) {
      int bb = tid >> 5, j = tid & 31;
      float ghr = ghsh[ j       * 5 + bb] + bsh[j];
      float ghz = ghsh[(32 + j) * 5 + bb] + bsh[32 + j];
      float ghn = ghsh[(64 + j) * 5 + bb] + bsh[64 + j];
      float rg = 1.f / (1.f + expf(-(gxr + ghr)));
      float zg = 1.f / (1.f + expf(-(gxz + ghz)));
      float ng = tanhf(gxn + rg * ghn);
      float hp = hsh[bb * HSTR + j0 + j];
      float hnew = (1.f - zg) * ng + zg * hp;
      __hip_atomic_store(
          (unsigned*)(hist + ((size_t)(bbase + bb) * T_ + t) * H_) + j0 + j,
          __float_as_uint(hnew), __ATOMIC_RELAXED, __HIP_MEMORY_SCOPE_AGENT);
    }
    __syncthreads();   // protect hsh/ghsh reuse next step
  }
}

// ---------------- sentinel fill: hist rows [t0, t0+tc) for all batches ----
__global__ __launch_bounds__(256) void sent_fill(float* hist, int t0, int tc) {
  int i = blockIdx.x * 256 + threadIdx.x;          // uint4 index
  int per = tc * (H_ >> 2);                        // uint4 per batch
  if (i < B_ * per) {
    int b = i / per, r = i % per;
    uint4* p = (uint4*)(hist + ((size_t)b * T_ + t0) * H_) + r;
    *p = make_uint4(SENT, SENT, SENT, SENT);
  }
}

// ---------------- fp32 -> bf16 hi/lo split ----------------
__device__ __forceinline__ unsigned short f2bf_rne(float f) {
  unsigned u = __float_as_uint(f);
  unsigned r = (u + 0x7fffu + ((u >> 16) & 1u)) >> 16;
  return (unsigned short)r;
}
__device__ __forceinline__ float bf2f(unsigned short h) {
  return __uint_as_float(((unsigned)h) << 16);
}

__global__ __launch_bounds__(256) void conv_split(
    const float* __restrict__ A, int lda, int t0, int tc, int ltc,
    unsigned short* __restrict__ Ah, unsigned short* __restrict__ Al)
{
  int idx = blockIdx.x * 256 + threadIdx.x;
  int m = idx / (lda >> 2), kq = idx % (lda >> 2);
  const float4 v = *(const float4*)
      (A + ((size_t)(m >> ltc) * T_ + t0 + (m & (tc - 1))) * lda + (kq << 2));
  unsigned short h0 = f2bf_rne(v.x), h1 = f2bf_rne(v.y),
                 h2 = f2bf_rne(v.z), h3 = f2bf_rne(v.w);
  unsigned short l0 = f2bf_rne(v.x - bf2f(h0)), l1 = f2bf_rne(v.y - bf2f(h1)),
                 l2 = f2bf_rne(v.z - bf2f(h2)), l3 = f2bf_rne(v.w - bf2f(h3));
  size_t o = (size_t)m * lda + (kq << 2);
  *(ushort4*)(Ah + o) = make_ushort4(h0, h1, h2, h3);
  *(ushort4*)(Al + o) = make_ushort4(l0, l1, l2, l3);
}

// ---------------- split-bf16 MFMA GEMM (double-buffered, pipelined) -------
__global__ __launch_bounds__(256, 2) void gemm_mfma(
    const unsigned short* __restrict__ Ah, const unsigned short* __restrict__ Al,
    const unsigned short* __restrict__ Bh, const unsigned short* __restrict__ Bl,
    const float* __restrict__ bias, float* __restrict__ gxout, int K)
{
  __shared__ unsigned short sAh[2][128 * BKg], sAl[2][128 * BKg];
  __shared__ unsigned short sBh[2][128 * BKg], sBl[2][128 * BKg];

  const int tid = threadIdx.x;
  const int m0 = blockIdx.x << 7, n0 = blockIdx.y << 7;
  const int wave = tid >> 6, lane = tid & 63;
  const int wr = (wave & 1) << 6, wc = (wave >> 1) << 6;
  const int fm = lane & 15, kh = lane >> 4;

  const int srow = tid >> 2, sq = tid & 3;
  const int lofs0 = srow * BKg + (sq << 3);
  const int lofs1 = (64 + srow) * BKg + (sq << 3);

  f32x4 acc[4][4];
  #pragma unroll
  for (int i = 0; i < 4; ++i)
    #pragma unroll
    for (int j = 0; j < 4; ++j)
      acc[i][j] = (f32x4){0.f, 0.f, 0.f, 0.f};

  float4 pAh[2], pAl[2], pBh[2], pBl[2];
  #define PREFETCH(k0)                                                        \
    {                                                                         \
      size_t a0 = (size_t)(m0 + srow) * K + (k0) + (sq << 3);                 \
      size_t a1 = (size_t)(m0 + 64 + srow) * K + (k0) + (sq << 3);            \
      size_t b0 = (size_t)(n0 + srow) * K + (k0) + (sq << 3);                 \
      size_t b1 = (size_t)(n0 + 64 + srow) * K + (k0) + (sq << 3);            \
      pAh[0] = *(const float4*)&Ah[a0]; pAh[1] = *(const float4*)&Ah[a1];     \
      pAl[0] = *(const float4*)&Al[a0]; pAl[1] = *(const float4*)&Al[a1];     \
      pBh[0] = *(const float4*)&Bh[b0]; pBh[1] = *(const float4*)&Bh[b1];     \
      pBl[0] = *(const float4*)&Bl[b0]; pBl[1] = *(const float4*)&Bl[b1];     \
    }
  #define STORE_LDS(buf)                                                      \
    {                                                                         \
      *(float4*)&sAh[buf][lofs0] = pAh[0]; *(float4*)&sAh[buf][lofs1] = pAh[1];\
      *(float4*)&sAl[buf][lofs0] = pAl[0]; *(float4*)&sAl[buf][lofs1] = pAl[1];\
      *(float4*)&sBh[buf][lofs0] = pBh[0]; *(float4*)&sBh[buf][lofs1] = pBh[1];\
      *(float4*)&sBl[buf][lofs0] = pBl[0]; *(float4*)&sBl[buf][lofs1] = pBl[1];\
    }

  PREFETCH(0);
  STORE_LDS(0);
  int buf = 0;

  for (int k0 = 0; k0 < K; k0 += BKg) {
    __syncthreads();
    const bool more = (k0 + BKg) < K;
    if (more) PREFETCH(k0 + BKg);

    short8 fAh[4], fAl[4], fBh[4], fBl[4];
    #pragma unroll
    for (int i = 0; i < 4; ++i) {
      int ao = (wr + i * 16 + fm) * BKg + (kh << 3);
      int bo = (wc + i * 16 + fm) * BKg + (kh << 3);
      fAh[i] = *(const short8*)&sAh[buf][ao];
      fAl[i] = *(const short8*)&sAl[buf][ao];
      fBh[i] = *(const short8*)&sBh[buf][bo];
      fBl[i] = *(const short8*)&sBl[buf][bo];
    }
    #pragma unroll
    for (int i = 0; i < 4; ++i)
      #pragma unroll
      for (int j = 0; j < 4; ++j) {
        acc[i][j] = __builtin_amdgcn_mfma_f32_16x16x32_bf16(
            fAh[i], fBh[j], acc[i][j], 0, 0, 0);
        acc[i][j] = __builtin_amdgcn_mfma_f32_16x16x32_bf16(
            fAh[i], fBl[j], acc[i][j], 0, 0, 0);
        acc[i][j] = __builtin_amdgcn_mfma_f32_16x16x32_bf16(
            fAl[i], fBh[j], acc[i][j], 0, 0, 0);
      }
    if (more) {
      STORE_LDS(buf ^ 1);
      buf ^= 1;
    }
  }

  #pragma unroll
  for (int j = 0; j < 4; ++j) {
    int col = n0 + wc + j * 16 + fm;
    float bv = bias[col];
    #pragma unroll
    for (int i = 0; i < 4; ++i) {
      int rowb = m0 + wr + i * 16 + (kh << 2);
      #pragma unroll
      for (int r = 0; r < 4; ++r)
        gxout[(size_t)(rowb + r) * G3_ + col] = acc[i][j][r] + bv;
    }
  }
}

// ---------------- final FC ----------------
__global__ void fc_kernel(const float* __restrict__ hist, const float* __restrict__ Wfc,
                          const float* __restrict__ bfc, float* __restrict__ out)
{
  int b = blockIdx.x, lane = threadIdx.x;
  const float* h = hist + ((size_t)b*T_ + (T_-1))*H_;
  float acc = 0.f;
  for (int j = lane; j < H_; j += 64) acc += h[j]*Wfc[j];
  #pragma unroll
  for (int off = 32; off; off >>= 1) acc += __shfl_down(acc, off, 64);
  if (lane == 0) out[b] = acc + bfc[0];
}

extern "C" void kernel_launch(void* const* d_in, const int* in_sizes, int n_in,
                              void* d_out, int out_size, void* d_ws, size_t ws_size,
                              hipStream_t stream)
{
  const float* X    = (const float*)d_in[0];
  const float* Wih0 = (const float*)d_in[1];
  const float* Whh0 = (const float*)d_in[2];
  const float* bih0 = (const float*)d_in[3];
  const float* bhh0 = (const float*)d_in[4];
  const float* Wih1 = (const float*)d_in[5];
  const float* Whh1 = (const float*)d_in[6];
  const float* bih1 = (const float*)d_in[7];
  const float* bhh1 = (const float*)d_in[8];
  const float* Wfc  = (const float*)d_in[9];
  const float* bfc  = (const float*)d_in[10];

  float* hist = (float*)((char*)d_ws + 4096);
  const size_t histB = (size_t)B_*T_*H_*4;

  const size_t bB = (size_t)G3_ * 512 * 2;
  int tcg = 128;
  {
    size_t fixed = 4096 + histB + 2 * bB;
    if      (ws_size >= fixed + (size_t)B_*512*((size_t)G3_*4 + 512*4)) tcg = 512;
    else if (ws_size >= fixed + (size_t)B_*256*((size_t)G3_*4 + 512*4)) tcg = 256;
  }
  int ltc = 31 - __builtin_clz((unsigned)tcg);

  float* gxbuf = (float*)((char*)d_ws + 4096 + histB);
  const size_t gxB = (size_t)B_*tcg*G3_*4;
  unsigned short* Ahb = (unsigned short*)((char*)gxbuf + gxB);
  const size_t aB = (size_t)B_*tcg*512*2;
  unsigned short* Alb = (unsigned short*)((char*)Ahb + aB);
  unsigned short* Bhb = (unsigned short*)((char*)Alb + aB);
  unsigned short* Blb = (unsigned short*)((char*)Bhb + bB);

  const int sentGridFull = (B_ * T_ * (H_ >> 2) + 255) / 256;
  const int sentGridChunk = (B_ * tcg * (H_ >> 2) + 255) / 256;

  // layer 0: whole hist -> sentinel before its first scan (conv/gemm read X)
  hipLaunchKernelGGL(sent_fill, dim3(sentGridFull), dim3(256), 0, stream,
                     hist, 0, T_);

  for (int lay = 0; lay < 2; ++lay) {
    const float* A   = lay ? (const float*)hist : X;
    int lda          = lay ? H_ : D0_;
    const float* Wih = lay ? Wih1 : Wih0;
    const float* bih = lay ? bih1 : bih0;
    const float* Whh = lay ? Whh1 : Whh0;
    const float* bhh = lay ? bhh1 : bhh0;

    hipLaunchKernelGGL(conv_split, dim3((G3_*lda/4)/256), dim3(256), 0, stream,
                       Wih, lda, 0, 1 << 30, 30, Bhb, Blb);

    for (int t0g = 0; t0g < T_; t0g += tcg) {
      int M = B_ * tcg;
      // conv reads this chunk's hist rows (layer 1) BEFORE they're sentineled
      hipLaunchKernelGGL(conv_split, dim3((M*lda/4)/256), dim3(256), 0, stream,
                         A, lda, t0g, tcg, ltc, Ahb, Alb);
      if (lay == 1)   // re-sentinel the rows this chunk's scan will write
        hipLaunchKernelGGL(sent_fill, dim3(sentGridChunk), dim3(256), 0, stream,
                           hist, t0g, tcg);
      dim3 ggrid(M >> 7, G3_ >> 7);
      hipLaunchKernelGGL(gemm_mfma, ggrid, dim3(256), 0, stream,
                         Ahb, Alb, Bhb, Blb, bih, gxbuf, lda);
      hipLaunchKernelGGL(scan_kernel, dim3(256), dim3(384), 0, stream,
                         Whh, bhh, (const float*)gxbuf, hist, t0g, tcg, t0g, tcg);
    }
  }

  hipLaunchKernelGGL(fc_kernel, dim3(64), dim3(64), 0, stream,
                     (const float*)hist, Wfc, bfc, (float*)d_out);
}

// Round 11
// 4685.449 us; speedup vs baseline: 8.1519x; 8.1519x over previous
//
#include <hip/hip_runtime.h>
#include <math.h>

#define B_  64
#define T_  512
#define D0_ 128
#define H_  512
#define G3_ 1536
#define HSTR 512
#define BKg 32
#define SENT 0x7FC00000u   // NaN sentinel; |h|<1 strictly so real h never matches

typedef short short8 __attribute__((ext_vector_type(8)));
typedef float f32x4 __attribute__((ext_vector_type(4)));

__device__ __forceinline__ float fast_sig(float x) {
  return __builtin_amdgcn_rcpf(1.f + __expf(-x));
}
__device__ __forceinline__ float fast_tanh(float x) {
  // 1 - 2/(1+e^{2x}); saturates correctly at +/-inf
  return 1.f - 2.f * __builtin_amdgcn_rcpf(1.f + __expf(2.f * x));
}

// ---------------- scan kernel (R8 tiling + overlap tweaks) ----------------
// 256 blocks = 16 groups x 16 blocks; plain launch; data-as-flag exchange
// (hist pre-filled with SENT; consumers poll h words; producer stores are
// the signal). Tiling: 2 rows x 64 k per thread -- PROVEN 104 VGPR.
// HARD CONSTRAINT (R4+R9): 4 rows x 32 k (128 W-regs) ALWAYS spills; the
// compiler caps 6-wave blocks at 128 VGPRs regardless of launch_bounds.
// New in R10: parity-double-buffered hsh/ghsh (no trailing sync -> gate
// waves overlap with next step's polling), fast-math gates, paired b64
// h-stores (atomic pair arrival for the b64 pair-poll).
__global__ __launch_bounds__(384, 2) void scan_kernel(
    const float* __restrict__ Whh, const float* __restrict__ bhh,
    const float* __restrict__ gx, float* __restrict__ hist,
    int t0, int tc, int gxt0, int gxT)
{
  __shared__ float hsh[2][4 * HSTR];
  __shared__ float ghsh[2][96 * 5];
  __shared__ float bsh[96];

  const int tid = threadIdx.x;
  const int blk = blockIdx.x;
  const int g = blk >> 4, c = blk & 15;
  const int j0 = c << 5;
  const int bbase = g << 2;

  const int rp = tid >> 3, s = tid & 7;
  const int r0 = rp, r1 = rp + 48;
  const int grow0 = (r0 >> 5) * H_ + j0 + (r0 & 31);
  const int grow1 = (r1 >> 5) * H_ + j0 + (r1 & 31);

  float w0[64], w1[64];
  {
    const float* R0 = Whh + (size_t)grow0 * H_ + (s << 2);
    const float* R1 = Whh + (size_t)grow1 * H_ + (s << 2);
    #pragma unroll
    for (int kk = 0; kk < 16; ++kk) {
      *(float4*)&w0[kk * 4] = *(const float4*)(R0 + kk * 32);
      *(float4*)&w1[kk * 4] = *(const float4*)(R1 + kk * 32);
    }
  }
  if (tid < 96)
    bsh[tid] = bhh[(tid >> 5) * H_ + j0 + (tid & 31)];

  size_t go0 = 0;
  if (tid < 128) {
    int bb = tid >> 5, j = tid & 31;
    go0 = ((size_t)(bbase + bb) * gxT) * (size_t)G3_ + j0 + j;
  }
  __syncthreads();

  for (int t = t0; t < t0 + tc; ++t) {
    const int pb = t & 1;
    float* hs = hsh[pb];
    float* gs = ghsh[pb];

    // ---- gx prefetch (independent of exchange) ----
    float gxr = 0.f, gxz = 0.f, gxn = 0.f;
    if (tid < 128) {
      size_t go = go0 + (size_t)(t - gxt0) * (size_t)G3_;
      gxr = gx[go]; gxz = gx[go + 512]; gxn = gx[go + 1024];
    }

    // ---- stage h_prev into LDS: poll b64 pairs of the data itself ----
    if (t == 0) {
      for (int idx = tid; idx < 2048; idx += 384)
        hs[(idx >> 9) * HSTR + (idx & 511)] = 0.f;
    } else {
      unsigned rem = 0;
      #pragma unroll
      for (int p = 0; p < 3; ++p)
        if (tid + p * 384 < 1024) rem |= 1u << p;
      unsigned long long vals[3];
      while (rem) {
        #pragma unroll
        for (int p = 0; p < 3; ++p)
          if (rem & (1u << p)) {
            int idx = tid + p * 384;              // pair index
            int bb = idx >> 8, e2 = idx & 255;    // batch, pair-in-row
            vals[p] = __hip_atomic_load(
                (const unsigned long long*)(hist +
                    ((size_t)(bbase + bb) * T_ + (t - 1)) * H_) + e2,
                __ATOMIC_RELAXED, __HIP_MEMORY_SCOPE_AGENT);
          }
        #pragma unroll
        for (int p = 0; p < 3; ++p)
          if (rem & (1u << p)) {
            unsigned lo = (unsigned)vals[p], hi = (unsigned)(vals[p] >> 32);
            if (lo != SENT && hi != SENT) {   // b64 producer => pair atomic
              int idx = tid + p * 384;
              int bb = idx >> 8, e2 = idx & 255;
              *(float2*)&hs[bb * HSTR + (e2 << 1)] =
                  make_float2(__uint_as_float(lo), __uint_as_float(hi));
              rem &= ~(1u << p);
            }
          }
      }
    }
    __syncthreads();   // SYNC1: hs staged

    // ---- dots: 2 rows x 4 batches, k-slice of 64 per thread ----
    float acc0[4], acc1[4];
    #pragma unroll
    for (int b = 0; b < 4; ++b) {
      const float* hb = hs + b * HSTR + (s << 2);
      float a00 = 0.f, a01 = 0.f, a10 = 0.f, a11 = 0.f;
      #pragma unroll
      for (int kk = 0; kk < 16; kk += 2) {
        float4 h0 = *(const float4*)(hb + kk * 32);
        float4 h1 = *(const float4*)(hb + kk * 32 + 32);
        a00 += w0[kk*4+0]*h0.x; a00 += w0[kk*4+1]*h0.y;
        a00 += w0[kk*4+2]*h0.z; a00 += w0[kk*4+3]*h0.w;
        a10 += w1[kk*4+0]*h0.x; a10 += w1[kk*4+1]*h0.y;
        a10 += w1[kk*4+2]*h0.z; a10 += w1[kk*4+3]*h0.w;
        a01 += w0[kk*4+4]*h1.x; a01 += w0[kk*4+5]*h1.y;
        a01 += w0[kk*4+6]*h1.z; a01 += w0[kk*4+7]*h1.w;
        a11 += w1[kk*4+4]*h1.x; a11 += w1[kk*4+5]*h1.y;
        a11 += w1[kk*4+6]*h1.z; a11 += w1[kk*4+7]*h1.w;
      }
      acc0[b] = a00 + a01;
      acc1[b] = a10 + a11;
    }

    #pragma unroll
    for (int m = 1; m < 8; m <<= 1) {
      #pragma unroll
      for (int b = 0; b < 4; ++b) {
        acc0[b] += __shfl_xor(acc0[b], m, 64);
        acc1[b] += __shfl_xor(acc1[b], m, 64);
      }
    }
    if (s < 4) {
      float v0 = (s & 2) ? ((s & 1) ? acc0[3] : acc0[2])
                         : ((s & 1) ? acc0[1] : acc0[0]);
      float v1 = (s & 2) ? ((s & 1) ? acc1[3] : acc1[2])
                         : ((s & 1) ? acc1[1] : acc1[0]);
      gs[r0 * 5 + s] = v0;
      gs[r1 * 5 + s] = v1;
    }
    __syncthreads();   // SYNC2: gs complete

    // ---- gates + h_new (waves 0-1); waves 2-5 fall through to next poll --
    if (tid < 128) {
      int bb = tid >> 5, j = tid & 31;
      float ghr = gs[ j       * 5 + bb] + bsh[j];
      float ghz = gs[(32 + j) * 5 + bb] + bsh[32 + j];
      float ghn = gs[(64 + j) * 5 + bb] + bsh[64 + j];
      float rg = fast_sig(gxr + ghr);
      float zg = fast_sig(gxz + ghz);
      float ng = fast_tanh(gxn + rg * ghn);
      float hp = hs[bb * HSTR + j0 + j];
      float hnew = (1.f - zg) * ng + zg * hp;
      // pack (j even, j odd) -> single b64 store: half the stores, and the
      // consumer's pair-poll sees both words arrive atomically.
      float hup = __shfl_down(hnew, 1, 64);
      if (!(tid & 1)) {
        unsigned long long pk =
            ((unsigned long long)__float_as_uint(hup) << 32) |
            (unsigned long long)__float_as_uint(hnew);
        __hip_atomic_store(
            (unsigned long long*)(hist + ((size_t)(bbase + bb) * T_ + t) * H_)
                + ((j0 + j) >> 1),
            pk, __ATOMIC_RELAXED, __HIP_MEMORY_SCOPE_AGENT);
      }
    }
    // no trailing sync: parity buffers make next-step staging safe; gate
    // latency overlaps with waves 2-5 already polling step t+1.
  }
}

// ---------------- sentinel fill: hist rows [t0, t0+tc) for all batches ----
__global__ __launch_bounds__(256) void sent_fill(float* hist, int t0, int tc) {
  int i = blockIdx.x * 256 + threadIdx.x;          // uint4 index
  int per = tc * (H_ >> 2);                        // uint4 per batch
  if (i < B_ * per) {
    int b = i / per, r = i % per;
    uint4* p = (uint4*)(hist + ((size_t)b * T_ + t0) * H_) + r;
    *p = make_uint4(SENT, SENT, SENT, SENT);
  }
}

// ---------------- fp32 -> bf16 hi/lo split ----------------
__device__ __forceinline__ unsigned short f2bf_rne(float f) {
  unsigned u = __float_as_uint(f);
  unsigned r = (u + 0x7fffu + ((u >> 16) & 1u)) >> 16;
  return (unsigned short)r;
}
__device__ __forceinline__ float bf2f(unsigned short h) {
  return __uint_as_float(((unsigned)h) << 16);
}

__global__ __launch_bounds__(256) void conv_split(
    const float* __restrict__ A, int lda, int t0, int tc, int ltc,
    unsigned short* __restrict__ Ah, unsigned short* __restrict__ Al)
{
  int idx = blockIdx.x * 256 + threadIdx.x;
  int m = idx / (lda >> 2), kq = idx % (lda >> 2);
  const float4 v = *(const float4*)
      (A + ((size_t)(m >> ltc) * T_ + t0 + (m & (tc - 1))) * lda + (kq << 2));
  unsigned short h0 = f2bf_rne(v.x), h1 = f2bf_rne(v.y),
                 h2 = f2bf_rne(v.z), h3 = f2bf_rne(v.w);
  unsigned short l0 = f2bf_rne(v.x - bf2f(h0)), l1 = f2bf_rne(v.y - bf2f(h1)),
                 l2 = f2bf_rne(v.z - bf2f(h2)), l3 = f2bf_rne(v.w - bf2f(h3));
  size_t o = (size_t)m * lda + (kq << 2);
  *(ushort4*)(Ah + o) = make_ushort4(h0, h1, h2, h3);
  *(ushort4*)(Al + o) = make_ushort4(l0, l1, l2, l3);
}

// ---------------- split-bf16 MFMA GEMM (double-buffered, pipelined) -------
__global__ __launch_bounds__(256, 2) void gemm_mfma(
    const unsigned short* __restrict__ Ah, const unsigned short* __restrict__ Al,
    const unsigned short* __restrict__ Bh, const unsigned short* __restrict__ Bl,
    const float* __restrict__ bias, float* __restrict__ gxout, int K)
{
  __shared__ unsigned short sAh[2][128 * BKg], sAl[2][128 * BKg];
  __shared__ unsigned short sBh[2][128 * BKg], sBl[2][128 * BKg];

  const int tid = threadIdx.x;
  const int m0 = blockIdx.x << 7, n0 = blockIdx.y << 7;
  const int wave = tid >> 6, lane = tid & 63;
  const int wr = (wave & 1) << 6, wc = (wave >> 1) << 6;
  const int fm = lane & 15, kh = lane >> 4;

  const int srow = tid >> 2, sq = tid & 3;
  const int lofs0 = srow * BKg + (sq << 3);
  const int lofs1 = (64 + srow) * BKg + (sq << 3);

  f32x4 acc[4][4];
  #pragma unroll
  for (int i = 0; i < 4; ++i)
    #pragma unroll
    for (int j = 0; j < 4; ++j)
      acc[i][j] = (f32x4){0.f, 0.f, 0.f, 0.f};

  float4 pAh[2], pAl[2], pBh[2], pBl[2];
  #define PREFETCH(k0)                                                        \
    {                                                                         \
      size_t a0 = (size_t)(m0 + srow) * K + (k0) + (sq << 3);                 \
      size_t a1 = (size_t)(m0 + 64 + srow) * K + (k0) + (sq << 3);            \
      size_t b0 = (size_t)(n0 + srow) * K + (k0) + (sq << 3);                 \
      size_t b1 = (size_t)(n0 + 64 + srow) * K + (k0) + (sq << 3);            \
      pAh[0] = *(const float4*)&Ah[a0]; pAh[1] = *(const float4*)&Ah[a1];     \
      pAl[0] = *(const float4*)&Al[a0]; pAl[1] = *(const float4*)&Al[a1];     \
      pBh[0] = *(const float4*)&Bh[b0]; pBh[1] = *(const float4*)&Bh[b1];     \
      pBl[0] = *(const float4*)&Bl[b0]; pBl[1] = *(const float4*)&Bl[b1];     \
    }
  #define STORE_LDS(buf)                                                      \
    {                                                                         \
      *(float4*)&sAh[buf][lofs0] = pAh[0]; *(float4*)&sAh[buf][lofs1] = pAh[1];\
      *(float4*)&sAl[buf][lofs0] = pAl[0]; *(float4*)&sAl[buf][lofs1] = pAl[1];\
      *(float4*)&sBh[buf][lofs0] = pBh[0]; *(float4*)&sBh[buf][lofs1] = pBh[1];\
      *(float4*)&sBl[buf][lofs0] = pBl[0]; *(float4*)&sBl[buf][lofs1] = pBl[1];\
    }

  PREFETCH(0);
  STORE_LDS(0);
  int buf = 0;

  for (int k0 = 0; k0 < K; k0 += BKg) {
    __syncthreads();
    const bool more = (k0 + BKg) < K;
    if (more) PREFETCH(k0 + BKg);

    short8 fAh[4], fAl[4], fBh[4], fBl[4];
    #pragma unroll
    for (int i = 0; i < 4; ++i) {
      int ao = (wr + i * 16 + fm) * BKg + (kh << 3);
      int bo = (wc + i * 16 + fm) * BKg + (kh << 3);
      fAh[i] = *(const short8*)&sAh[buf][ao];
      fAl[i] = *(const short8*)&sAl[buf][ao];
      fBh[i] = *(const short8*)&sBh[buf][bo];
      fBl[i] = *(const short8*)&sBl[buf][bo];
    }
    #pragma unroll
    for (int i = 0; i < 4; ++i)
      #pragma unroll
      for (int j = 0; j < 4; ++j) {
        acc[i][j] = __builtin_amdgcn_mfma_f32_16x16x32_bf16(
            fAh[i], fBh[j], acc[i][j], 0, 0, 0);
        acc[i][j] = __builtin_amdgcn_mfma_f32_16x16x32_bf16(
            fAh[i], fBl[j], acc[i][j], 0, 0, 0);
        acc[i][j] = __builtin_amdgcn_mfma_f32_16x16x32_bf16(
            fAl[i], fBh[j], acc[i][j], 0, 0, 0);
      }
    if (more) {
      STORE_LDS(buf ^ 1);
      buf ^= 1;
    }
  }

  #pragma unroll
  for (int j = 0; j < 4; ++j) {
    int col = n0 + wc + j * 16 + fm;
    float bv = bias[col];
    #pragma unroll
    for (int i = 0; i < 4; ++i) {
      int rowb = m0 + wr + i * 16 + (kh << 2);
      #pragma unroll
      for (int r = 0; r < 4; ++r)
        gxout[(size_t)(rowb + r) * G3_ + col] = acc[i][j][r] + bv;
    }
  }
}

// ---------------- final FC ----------------
__global__ void fc_kernel(const float* __restrict__ hist, const float* __restrict__ Wfc,
                          const float* __restrict__ bfc, float* __restrict__ out)
{
  int b = blockIdx.x, lane = threadIdx.x;
  const float* h = hist + ((size_t)b*T_ + (T_-1))*H_;
  float acc = 0.f;
  for (int j = lane; j < H_; j += 64) acc += h[j]*Wfc[j];
  #pragma unroll
  for (int off = 32; off; off >>= 1) acc += __shfl_down(acc, off, 64);
  if (lane == 0) out[b] = acc + bfc[0];
}

extern "C" void kernel_launch(void* const* d_in, const int* in_sizes, int n_in,
                              void* d_out, int out_size, void* d_ws, size_t ws_size,
                              hipStream_t stream)
{
  const float* X    = (const float*)d_in[0];
  const float* Wih0 = (const float*)d_in[1];
  const float* Whh0 = (const float*)d_in[2];
  const float* bih0 = (const float*)d_in[3];
  const float* bhh0 = (const float*)d_in[4];
  const float* Wih1 = (const float*)d_in[5];
  const float* Whh1 = (const float*)d_in[6];
  const float* bih1 = (const float*)d_in[7];
  const float* bhh1 = (const float*)d_in[8];
  const float* Wfc  = (const float*)d_in[9];
  const float* bfc  = (const float*)d_in[10];

  float* hist = (float*)((char*)d_ws + 4096);
  const size_t histB = (size_t)B_*T_*H_*4;

  const size_t bB = (size_t)G3_ * 512 * 2;
  int tcg = 128;
  {
    size_t fixed = 4096 + histB + 2 * bB;
    if      (ws_size >= fixed + (size_t)B_*512*((size_t)G3_*4 + 512*4)) tcg = 512;
    else if (ws_size >= fixed + (size_t)B_*256*((size_t)G3_*4 + 512*4)) tcg = 256;
  }
  int ltc = 31 - __builtin_clz((unsigned)tcg);

  float* gxbuf = (float*)((char*)d_ws + 4096 + histB);
  const size_t gxB = (size_t)B_*tcg*G3_*4;
  unsigned short* Ahb = (unsigned short*)((char*)gxbuf + gxB);
  const size_t aB = (size_t)B_*tcg*512*2;
  unsigned short* Alb = (unsigned short*)((char*)Ahb + aB);
  unsigned short* Bhb = (unsigned short*)((char*)Alb + aB);
  unsigned short* Blb = (unsigned short*)((char*)Bhb + bB);

  const int sentGridFull = (B_ * T_ * (H_ >> 2) + 255) / 256;
  const int sentGridChunk = (B_ * tcg * (H_ >> 2) + 255) / 256;

  // layer 0: whole hist -> sentinel before its first scan (conv/gemm read X)
  hipLaunchKernelGGL(sent_fill, dim3(sentGridFull), dim3(256), 0, stream,
                     hist, 0, T_);

  for (int lay = 0; lay < 2; ++lay) {
    const float* A   = lay ? (const float*)hist : X;
    int lda          = lay ? H_ : D0_;
    const float* Wih = lay ? Wih1 : Wih0;
    const float* bih = lay ? bih1 : bih0;
    const float* Whh = lay ? Whh1 : Whh0;
    const float* bhh = lay ? bhh1 : bhh0;

    hipLaunchKernelGGL(conv_split, dim3((G3_*lda/4)/256), dim3(256), 0, stream,
                       Wih, lda, 0, 1 << 30, 30, Bhb, Blb);

    for (int t0g = 0; t0g < T_; t0g += tcg) {
      int M = B_ * tcg;
      // conv reads this chunk's hist rows (layer 1) BEFORE they're sentineled
      hipLaunchKernelGGL(conv_split, dim3((M*lda/4)/256), dim3(256), 0, stream,
                         A, lda, t0g, tcg, ltc, Ahb, Alb);
      if (lay == 1)   // re-sentinel the rows this chunk's scan will write
        hipLaunchKernelGGL(sent_fill, dim3(sentGridChunk), dim3(256), 0, stream,
                           hist, t0g, tcg);
      dim3 ggrid(M >> 7, G3_ >> 7);
      hipLaunchKernelGGL(gemm_mfma, ggrid, dim3(256), 0, stream,
                         Ahb, Alb, Bhb, Blb, bih, gxbuf, lda);
      hipLaunchKernelGGL(scan_kernel, dim3(256), dim3(384), 0, stream,
                         Whh, bhh, (const float*)gxbuf, hist, t0g, tcg, t0g, tcg);
    }
  }

  hipLaunchKernelGGL(fc_kernel, dim3(64), dim3(64), 0, stream,
                     (const float*)hist, Wfc, bfc, (float*)d_out);
}

// Round 12
// 4196.478 us; speedup vs baseline: 9.1017x; 1.1165x over previous
//
#include <hip/hip_runtime.h>
#include <math.h>

#define B_  64
#define T_  512
#define D0_ 128
#define H_  512
#define G3_ 1536
#define HSTR 512
#define BKg 32
#define SENT 0x7FC00000u   // NaN sentinel; |h|<1 strictly so real h never matches

typedef short short8 __attribute__((ext_vector_type(8)));
typedef float f32x4 __attribute__((ext_vector_type(4)));

__device__ __forceinline__ float fast_sig(float x) {
  return __builtin_amdgcn_rcpf(1.f + __expf(-x));
}
__device__ __forceinline__ float fast_tanh(float x) {
  // 1 - 2/(1+e^{2x}); saturates correctly at +/-inf
  return 1.f - 2.f * __builtin_amdgcn_rcpf(1.f + __expf(2.f * x));
}

// ---------------- scan kernel (R8 structure + fast-math gates ONLY) --------
// 256 blocks = 16 groups x 16 blocks; plain launch; data-as-flag exchange
// (hist pre-filled with SENT; consumers poll h words; producer stores are
// the signal). Tiling: 2 rows x 64 k per thread -- PROVEN 104 VGPR.
// HARD CONSTRAINT (R4+R9): 4 rows x 32 k (128 W-regs) ALWAYS spills; the
// compiler caps 6-wave blocks at 128 VGPRs regardless of launch_bounds.
// LESSON (R10): do NOT remove the trailing sync / poll early -- extra
// guaranteed-miss poll passes raise L3 pressure and slow detection
// (FETCH +19%, dur +4%). Keep R8's barrier structure exactly.
__global__ __launch_bounds__(384, 2) void scan_kernel(
    const float* __restrict__ Whh, const float* __restrict__ bhh,
    const float* __restrict__ gx, float* __restrict__ hist,
    int t0, int tc, int gxt0, int gxT)
{
  __shared__ float hsh[4 * HSTR];
  __shared__ float ghsh[96 * 5];
  __shared__ float bsh[96];

  const int tid = threadIdx.x;
  const int blk = blockIdx.x;
  const int g = blk >> 4, c = blk & 15;
  const int j0 = c << 5;
  const int bbase = g << 2;

  const int rp = tid >> 3, s = tid & 7;
  const int r0 = rp, r1 = rp + 48;
  const int grow0 = (r0 >> 5) * H_ + j0 + (r0 & 31);
  const int grow1 = (r1 >> 5) * H_ + j0 + (r1 & 31);

  float w0[64], w1[64];
  {
    const float* R0 = Whh + (size_t)grow0 * H_ + (s << 2);
    const float* R1 = Whh + (size_t)grow1 * H_ + (s << 2);
    #pragma unroll
    for (int kk = 0; kk < 16; ++kk) {
      *(float4*)&w0[kk * 4] = *(const float4*)(R0 + kk * 32);
      *(float4*)&w1[kk * 4] = *(const float4*)(R1 + kk * 32);
    }
  }
  if (tid < 96)
    bsh[tid] = bhh[(tid >> 5) * H_ + j0 + (tid & 31)];

  size_t go0 = 0;
  if (tid < 128) {
    int bb = tid >> 5, j = tid & 31;
    go0 = ((size_t)(bbase + bb) * gxT) * (size_t)G3_ + j0 + j;
  }
  __syncthreads();

  for (int t = t0; t < t0 + tc; ++t) {
    // ---- gx prefetch (independent of exchange) ----
    float gxr = 0.f, gxz = 0.f, gxn = 0.f;
    if (tid < 128) {
      size_t go = go0 + (size_t)(t - gxt0) * (size_t)G3_;
      gxr = gx[go]; gxz = gx[go + 512]; gxn = gx[go + 1024];
    }

    // ---- stage h_prev into LDS: poll b64 pairs of the data itself ----
    if (t == 0) {
      for (int idx = tid; idx < 2048; idx += 384)
        hsh[(idx >> 9) * HSTR + (idx & 511)] = 0.f;
    } else {
      unsigned rem = 0;
      #pragma unroll
      for (int p = 0; p < 3; ++p)
        if (tid + p * 384 < 1024) rem |= 1u << p;
      unsigned long long vals[3];
      while (rem) {
        #pragma unroll
        for (int p = 0; p < 3; ++p)
          if (rem & (1u << p)) {
            int idx = tid + p * 384;              // pair index
            int bb = idx >> 8, e2 = idx & 255;    // batch, pair-in-row
            vals[p] = __hip_atomic_load(
                (const unsigned long long*)(hist +
                    ((size_t)(bbase + bb) * T_ + (t - 1)) * H_) + e2,
                __ATOMIC_RELAXED, __HIP_MEMORY_SCOPE_AGENT);
          }
        #pragma unroll
        for (int p = 0; p < 3; ++p)
          if (rem & (1u << p)) {
            unsigned lo = (unsigned)vals[p], hi = (unsigned)(vals[p] >> 32);
            if (lo != SENT && hi != SENT) {
              int idx = tid + p * 384;
              int bb = idx >> 8, e2 = idx & 255;
              *(float2*)&hsh[bb * HSTR + (e2 << 1)] =
                  make_float2(__uint_as_float(lo), __uint_as_float(hi));
              rem &= ~(1u << p);
            }
          }
      }
    }
    __syncthreads();

    // ---- dots: 2 rows x 4 batches, k-slice of 64 per thread ----
    float acc0[4], acc1[4];
    #pragma unroll
    for (int b = 0; b < 4; ++b) {
      const float* hb = hsh + b * HSTR + (s << 2);
      float a00 = 0.f, a01 = 0.f, a10 = 0.f, a11 = 0.f;
      #pragma unroll
      for (int kk = 0; kk < 16; kk += 2) {
        float4 h0 = *(const float4*)(hb + kk * 32);
        float4 h1 = *(const float4*)(hb + kk * 32 + 32);
        a00 += w0[kk*4+0]*h0.x; a00 += w0[kk*4+1]*h0.y;
        a00 += w0[kk*4+2]*h0.z; a00 += w0[kk*4+3]*h0.w;
        a10 += w1[kk*4+0]*h0.x; a10 += w1[kk*4+1]*h0.y;
        a10 += w1[kk*4+2]*h0.z; a10 += w1[kk*4+3]*h0.w;
        a01 += w0[kk*4+4]*h1.x; a01 += w0[kk*4+5]*h1.y;
        a01 += w0[kk*4+6]*h1.z; a01 += w0[kk*4+7]*h1.w;
        a11 += w1[kk*4+4]*h1.x; a11 += w1[kk*4+5]*h1.y;
        a11 += w1[kk*4+6]*h1.z; a11 += w1[kk*4+7]*h1.w;
      }
      acc0[b] = a00 + a01;
      acc1[b] = a10 + a11;
    }

    #pragma unroll
    for (int m = 1; m < 8; m <<= 1) {
      #pragma unroll
      for (int b = 0; b < 4; ++b) {
        acc0[b] += __shfl_xor(acc0[b], m, 64);
        acc1[b] += __shfl_xor(acc1[b], m, 64);
      }
    }
    if (s < 4) {
      float v0 = (s & 2) ? ((s & 1) ? acc0[3] : acc0[2])
                         : ((s & 1) ? acc0[1] : acc0[0]);
      float v1 = (s & 2) ? ((s & 1) ? acc1[3] : acc1[2])
                         : ((s & 1) ? acc1[1] : acc1[0]);
      ghsh[r0 * 5 + s] = v0;
      ghsh[r1 * 5 + s] = v1;
    }
    __syncthreads();

    // ---- gates + h_new; fast-math gates (serial critical path) ----
    if (tid < 128) {
      int bb = tid >> 5, j = tid & 31;
      float ghr = ghsh[ j       * 5 + bb] + bsh[j];
      float ghz = ghsh[(32 + j) * 5 + bb] + bsh[32 + j];
      float ghn = ghsh[(64 + j) * 5 + bb] + bsh[64 + j];
      float rg = fast_sig(gxr + ghr);
      float zg = fast_sig(gxz + ghz);
      float ng = fast_tanh(gxn + rg * ghn);
      float hp = hsh[bb * HSTR + j0 + j];
      float hnew = (1.f - zg) * ng + zg * hp;
      __hip_atomic_store(
          (unsigned*)(hist + ((size_t)(bbase + bb) * T_ + t) * H_) + j0 + j,
          __float_as_uint(hnew), __ATOMIC_RELAXED, __HIP_MEMORY_SCOPE_AGENT);
    }
    __syncthreads();   // protect hsh/ghsh reuse next step (R10: do not remove)
  }
}

// ---------------- sentinel fill: hist rows [t0, t0+tc) for all batches ----
__global__ __launch_bounds__(256) void sent_fill(float* hist, int t0, int tc) {
  int i = blockIdx.x * 256 + threadIdx.x;          // uint4 index
  int per = tc * (H_ >> 2);                        // uint4 per batch
  if (i < B_ * per) {
    int b = i / per, r = i % per;
    uint4* p = (uint4*)(hist + ((size_t)b * T_ + t0) * H_) + r;
    *p = make_uint4(SENT, SENT, SENT, SENT);
  }
}

// ---------------- fp32 -> bf16 hi/lo split ----------------
__device__ __forceinline__ unsigned short f2bf_rne(float f) {
  unsigned u = __float_as_uint(f);
  unsigned r = (u + 0x7fffu + ((u >> 16) & 1u)) >> 16;
  return (unsigned short)r;
}
__device__ __forceinline__ float bf2f(unsigned short h) {
  return __uint_as_float(((unsigned)h) << 16);
}

__global__ __launch_bounds__(256) void conv_split(
    const float* __restrict__ A, int lda, int t0, int tc, int ltc,
    unsigned short* __restrict__ Ah, unsigned short* __restrict__ Al)
{
  int idx = blockIdx.x * 256 + threadIdx.x;
  int m = idx / (lda >> 2), kq = idx % (lda >> 2);
  const float4 v = *(const float4*)
      (A + ((size_t)(m >> ltc) * T_ + t0 + (m & (tc - 1))) * lda + (kq << 2));
  unsigned short h0 = f2bf_rne(v.x), h1 = f2bf_rne(v.y),
                 h2 = f2bf_rne(v.z), h3 = f2bf_rne(v.w);
  unsigned short l0 = f2bf_rne(v.x - bf2f(h0)), l1 = f2bf_rne(v.y - bf2f(h1)),
                 l2 = f2bf_rne(v.z - bf2f(h2)), l3 = f2bf_rne(v.w - bf2f(h3));
  size_t o = (size_t)m * lda + (kq << 2);
  *(ushort4*)(Ah + o) = make_ushort4(h0, h1, h2, h3);
  *(ushort4*)(Al + o) = make_ushort4(l0, l1, l2, l3);
}

// ---------------- split-bf16 MFMA GEMM (double-buffered, pipelined) -------
__global__ __launch_bounds__(256, 2) void gemm_mfma(
    const unsigned short* __restrict__ Ah, const unsigned short* __restrict__ Al,
    const unsigned short* __restrict__ Bh, const unsigned short* __restrict__ Bl,
    const float* __restrict__ bias, float* __restrict__ gxout, int K)
{
  __shared__ unsigned short sAh[2][128 * BKg], sAl[2][128 * BKg];
  __shared__ unsigned short sBh[2][128 * BKg], sBl[2][128 * BKg];

  const int tid = threadIdx.x;
  const int m0 = blockIdx.x << 7, n0 = blockIdx.y << 7;
  const int wave = tid >> 6, lane = tid & 63;
  const int wr = (wave & 1) << 6, wc = (wave >> 1) << 6;
  const int fm = lane & 15, kh = lane >> 4;

  const int srow = tid >> 2, sq = tid & 3;
  const int lofs0 = srow * BKg + (sq << 3);
  const int lofs1 = (64 + srow) * BKg + (sq << 3);

  f32x4 acc[4][4];
  #pragma unroll
  for (int i = 0; i < 4; ++i)
    #pragma unroll
    for (int j = 0; j < 4; ++j)
      acc[i][j] = (f32x4){0.f, 0.f, 0.f, 0.f};

  float4 pAh[2], pAl[2], pBh[2], pBl[2];
  #define PREFETCH(k0)                                                        \
    {                                                                         \
      size_t a0 = (size_t)(m0 + srow) * K + (k0) + (sq << 3);                 \
      size_t a1 = (size_t)(m0 + 64 + srow) * K + (k0) + (sq << 3);            \
      size_t b0 = (size_t)(n0 + srow) * K + (k0) + (sq << 3);                 \
      size_t b1 = (size_t)(n0 + 64 + srow) * K + (k0) + (sq << 3);            \
      pAh[0] = *(const float4*)&Ah[a0]; pAh[1] = *(const float4*)&Ah[a1];     \
      pAl[0] = *(const float4*)&Al[a0]; pAl[1] = *(const float4*)&Al[a1];     \
      pBh[0] = *(const float4*)&Bh[b0]; pBh[1] = *(const float4*)&Bh[b1];     \
      pBl[0] = *(const float4*)&Bl[b0]; pBl[1] = *(const float4*)&Bl[b1];     \
    }
  #define STORE_LDS(buf)                                                      \
    {                                                                         \
      *(float4*)&sAh[buf][lofs0] = pAh[0]; *(float4*)&sAh[buf][lofs1] = pAh[1];\
      *(float4*)&sAl[buf][lofs0] = pAl[0]; *(float4*)&sAl[buf][lofs1] = pAl[1];\
      *(float4*)&sBh[buf][lofs0] = pBh[0]; *(float4*)&sBh[buf][lofs1] = pBh[1];\
      *(float4*)&sBl[buf][lofs0] = pBl[0]; *(float4*)&sBl[buf][lofs1] = pBl[1];\
    }

  PREFETCH(0);
  STORE_LDS(0);
  int buf = 0;

  for (int k0 = 0; k0 < K; k0 += BKg) {
    __syncthreads();
    const bool more = (k0 + BKg) < K;
    if (more) PREFETCH(k0 + BKg);

    short8 fAh[4], fAl[4], fBh[4], fBl[4];
    #pragma unroll
    for (int i = 0; i < 4; ++i) {
      int ao = (wr + i * 16 + fm) * BKg + (kh << 3);
      int bo = (wc + i * 16 + fm) * BKg + (kh << 3);
      fAh[i] = *(const short8*)&sAh[buf][ao];
      fAl[i] = *(const short8*)&sAl[buf][ao];
      fBh[i] = *(const short8*)&sBh[buf][bo];
      fBl[i] = *(const short8*)&sBl[buf][bo];
    }
    #pragma unroll
    for (int i = 0; i < 4; ++i)
      #pragma unroll
      for (int j = 0; j < 4; ++j) {
        acc[i][j] = __builtin_amdgcn_mfma_f32_16x16x32_bf16(
            fAh[i], fBh[j], acc[i][j], 0, 0, 0);
        acc[i][j] = __builtin_amdgcn_mfma_f32_16x16x32_bf16(
            fAh[i], fBl[j], acc[i][j], 0, 0, 0);
        acc[i][j] = __builtin_amdgcn_mfma_f32_16x16x32_bf16(
            fAl[i], fBh[j], acc[i][j], 0, 0, 0);
      }
    if (more) {
      STORE_LDS(buf ^ 1);
      buf ^= 1;
    }
  }

  #pragma unroll
  for (int j = 0; j < 4; ++j) {
    int col = n0 + wc + j * 16 + fm;
    float bv = bias[col];
    #pragma unroll
    for (int i = 0; i < 4; ++i) {
      int rowb = m0 + wr + i * 16 + (kh << 2);
      #pragma unroll
      for (int r = 0; r < 4; ++r)
        gxout[(size_t)(rowb + r) * G3_ + col] = acc[i][j][r] + bv;
    }
  }
}

// ---------------- final FC ----------------
__global__ void fc_kernel(const float* __restrict__ hist, const float* __restrict__ Wfc,
                          const float* __restrict__ bfc, float* __restrict__ out)
{
  int b = blockIdx.x, lane = threadIdx.x;
  const float* h = hist + ((size_t)b*T_ + (T_-1))*H_;
  float acc = 0.f;
  for (int j = lane; j < H_; j += 64) acc += h[j]*Wfc[j];
  #pragma unroll
  for (int off = 32; off; off >>= 1) acc += __shfl_down(acc, off, 64);
  if (lane == 0) out[b] = acc + bfc[0];
}

extern "C" void kernel_launch(void* const* d_in, const int* in_sizes, int n_in,
                              void* d_out, int out_size, void* d_ws, size_t ws_size,
                              hipStream_t stream)
{
  const float* X    = (const float*)d_in[0];
  const float* Wih0 = (const float*)d_in[1];
  const float* Whh0 = (const float*)d_in[2];
  const float* bih0 = (const float*)d_in[3];
  const float* bhh0 = (const float*)d_in[4];
  const float* Wih1 = (const float*)d_in[5];
  const float* Whh1 = (const float*)d_in[6];
  const float* bih1 = (const float*)d_in[7];
  const float* bhh1 = (const float*)d_in[8];
  const float* Wfc  = (const float*)d_in[9];
  const float* bfc  = (const float*)d_in[10];

  float* hist = (float*)((char*)d_ws + 4096);
  const size_t histB = (size_t)B_*T_*H_*4;

  const size_t bB = (size_t)G3_ * 512 * 2;
  int tcg = 128;
  {
    size_t fixed = 4096 + histB + 2 * bB;
    if      (ws_size >= fixed + (size_t)B_*512*((size_t)G3_*4 + 512*4)) tcg = 512;
    else if (ws_size >= fixed + (size_t)B_*256*((size_t)G3_*4 + 512*4)) tcg = 256;
  }
  int ltc = 31 - __builtin_clz((unsigned)tcg);

  float* gxbuf = (float*)((char*)d_ws + 4096 + histB);
  const size_t gxB = (size_t)B_*tcg*G3_*4;
  unsigned short* Ahb = (unsigned short*)((char*)gxbuf + gxB);
  const size_t aB = (size_t)B_*tcg*512*2;
  unsigned short* Alb = (unsigned short*)((char*)Ahb + aB);
  unsigned short* Bhb = (unsigned short*)((char*)Alb + aB);
  unsigned short* Blb = (unsigned short*)((char*)Bhb + bB);

  const int sentGridFull = (B_ * T_ * (H_ >> 2) + 255) / 256;
  const int sentGridChunk = (B_ * tcg * (H_ >> 2) + 255) / 256;

  // layer 0: whole hist -> sentinel before its first scan (conv/gemm read X)
  hipLaunchKernelGGL(sent_fill, dim3(sentGridFull), dim3(256), 0, stream,
                     hist, 0, T_);

  for (int lay = 0; lay < 2; ++lay) {
    const float* A   = lay ? (const float*)hist : X;
    int lda          = lay ? H_ : D0_;
    const float* Wih = lay ? Wih1 : Wih0;
    const float* bih = lay ? bih1 : bih0;
    const float* Whh = lay ? Whh1 : Whh0;
    const float* bhh = lay ? bhh1 : bhh0;

    hipLaunchKernelGGL(conv_split, dim3((G3_*lda/4)/256), dim3(256), 0, stream,
                       Wih, lda, 0, 1 << 30, 30, Bhb, Blb);

    for (int t0g = 0; t0g < T_; t0g += tcg) {
      int M = B_ * tcg;
      // conv reads this chunk's hist rows (layer 1) BEFORE they're sentineled
      hipLaunchKernelGGL(conv_split, dim3((M*lda/4)/256), dim3(256), 0, stream,
                         A, lda, t0g, tcg, ltc, Ahb, Alb);
      if (lay == 1)   // re-sentinel the rows this chunk's scan will write
        hipLaunchKernelGGL(sent_fill, dim3(sentGridChunk), dim3(256), 0, stream,
                           hist, t0g, tcg);
      dim3 ggrid(M >> 7, G3_ >> 7);
      hipLaunchKernelGGL(gemm_mfma, ggrid, dim3(256), 0, stream,
                         Ahb, Alb, Bhb, Blb, bih, gxbuf, lda);
      hipLaunchKernelGGL(scan_kernel, dim3(256), dim3(384), 0, stream,
                         Whh, bhh, (const float*)gxbuf, hist, t0g, tcg, t0g, tcg);
    }
  }

  hipLaunchKernelGGL(fc_kernel, dim3(64), dim3(64), 0, stream,
                     (const float*)hist, Wfc, bfc, (float*)d_out);
}